// Round 1
// 857.413 us; speedup vs baseline: 1.2320x; 1.2320x over previous
//
#include <hip/hip_runtime.h>

#define HID 128

typedef __bf16 bf16x8 __attribute__((ext_vector_type(8)));
typedef float  f32x4  __attribute__((ext_vector_type(4)));

__device__ __forceinline__ unsigned f2b(float x) {           // fp32 -> bf16 bits, RNE
    unsigned u = __float_as_uint(x);
    return (u + 0x7fffu + ((u >> 16) & 1u)) >> 16;
}
__device__ __forceinline__ float b2f(unsigned b) {           // bf16 bits -> fp32
    return __uint_as_float(b << 16);
}

// ---------------- CSR build ----------------
__global__ void deg_count_kernel(const int* __restrict__ dst, int* __restrict__ deg, int n_edges) {
    int e = blockIdx.x * blockDim.x + threadIdx.x;
    if (e < n_edges) atomicAdd(&deg[dst[e]], 1);
}

#define SCAN_BS 256
#define SCAN_ELEMS 1024  // 4 per thread

__global__ void scan1_kernel(const int* __restrict__ deg, int* __restrict__ excl,
                             int* __restrict__ blockSums, int n) {
    __shared__ int s[SCAN_BS];
    int base = blockIdx.x * SCAN_ELEMS + threadIdx.x * 4;
    int v[4]; int t = 0;
#pragma unroll
    for (int i = 0; i < 4; ++i) { int idx = base + i; v[i] = (idx < n) ? deg[idx] : 0; t += v[i]; }
    s[threadIdx.x] = t;
    __syncthreads();
    for (int off = 1; off < SCAN_BS; off <<= 1) {
        int x = (threadIdx.x >= off) ? s[threadIdx.x - off] : 0;
        __syncthreads();
        s[threadIdx.x] += x;
        __syncthreads();
    }
    int run = s[threadIdx.x] - t;
#pragma unroll
    for (int i = 0; i < 4; ++i) { int idx = base + i; if (idx < n) excl[idx] = run; run += v[i]; }
    if (threadIdx.x == SCAN_BS - 1) blockSums[blockIdx.x] = s[SCAN_BS - 1];
}

// single-block exclusive scan of blockSums (nb <= 256)
__global__ void scan2_kernel(int* __restrict__ bsums, int nb) {
    __shared__ int s[256];
    int i = threadIdx.x;
    int v = (i < nb) ? bsums[i] : 0;
    s[i] = v;
    __syncthreads();
    for (int off = 1; off < 256; off <<= 1) {
        int x = (i >= off) ? s[i - off] : 0;
        __syncthreads();
        s[i] += x;
        __syncthreads();
    }
    if (i < nb) bsums[i] = s[i] - v;
}

__global__ void scan3_kernel(int* __restrict__ rowptr, const int* __restrict__ blockSums,
                             int* __restrict__ cursor, const int* __restrict__ deg,
                             float* __restrict__ invd, int n) {
    int i = blockIdx.x * blockDim.x + threadIdx.x;
    if (i < n) {
        int v = rowptr[i] + blockSums[i >> 10];
        rowptr[i] = v;
        cursor[i] = v;
        invd[i] = 1.0f / fmaxf((float)deg[i], 1.0f);
    }
}

__global__ void fill_csr_kernel(const int* __restrict__ src, const int* __restrict__ dst,
                                int* __restrict__ cursor, int* __restrict__ csr_src, int n_edges) {
    int e = blockIdx.x * blockDim.x + threadIdx.x;
    if (e < n_edges) {
        int pos = atomicAdd(&cursor[dst[e]], 1);
        csr_src[pos] = src[e];
    }
}
// after fill_csr, cursor[i] == rowptr[i] + deg[i]  -> reused as row-end pointer

// ---------------- mask compaction: act[] = ordered list of mask==1 rows ----------------
__global__ void scatter_act_kernel(const int* __restrict__ mask, const int* __restrict__ excl,
                                   const int* __restrict__ bsums, int* __restrict__ act,
                                   int* __restrict__ n_act, int n) {
    int i = blockIdx.x * blockDim.x + threadIdx.x;
    if (i < n) {
        int pos = excl[i] + bsums[i >> 10];
        if (mask[i]) act[pos] = i;
        if (i == n - 1) *n_act = pos + (mask[i] ? 1 : 0);
    }
}

// inactive rows: h[row] = relu(gh[g2[row]])  (bf16 out). 16 threads per row, 8 cols each.
__global__ void fill_inactive_kernel(const int* __restrict__ mask, const int* __restrict__ g2,
                                     const float* __restrict__ gh, unsigned short* __restrict__ out,
                                     int n_nodes) {
    int idx = blockIdx.x * blockDim.x + threadIdx.x;
    int row = idx >> 4;
    if (row >= n_nodes || mask[row]) return;
    int c = (idx & 15) * 8;
    const float* src = gh + (size_t)g2[row] * HID + c;
    float4 v0 = reinterpret_cast<const float4*>(src)[0];
    float4 v1 = reinterpret_cast<const float4*>(src)[1];
    uint4 o;
    o.x = f2b(fmaxf(v0.x, 0.f)) | (f2b(fmaxf(v0.y, 0.f)) << 16);
    o.y = f2b(fmaxf(v0.z, 0.f)) | (f2b(fmaxf(v0.w, 0.f)) << 16);
    o.z = f2b(fmaxf(v1.x, 0.f)) | (f2b(fmaxf(v1.y, 0.f)) << 16);
    o.w = f2b(fmaxf(v1.z, 0.f)) | (f2b(fmaxf(v1.w, 0.f)) << 16);
    *reinterpret_cast<uint4*>(out + (size_t)row * HID + c) = o;
}

// ---------------- fp32 -> bf16 feature convert ----------------
__global__ void cvt_bf16_kernel(const float* __restrict__ in, unsigned short* __restrict__ out, int total4) {
    int i = blockIdx.x * blockDim.x + threadIdx.x;
    if (i >= total4) return;
    float4 v = reinterpret_cast<const float4*>(in)[i];
    uint2 o;
    o.x = f2b(v.x) | (f2b(v.y) << 16);
    o.y = f2b(v.z) | (f2b(v.w) << 16);
    reinterpret_cast<uint2*>(out)[i] = o;
}

// ---------------- weight prep: Wt[n][k] bf16, k = [Ws rows | Wn rows] ----------------
template<int NOUT>
__global__ void build_wt_kernel(const float* __restrict__ Ws, const float* __restrict__ Wn,
                                unsigned short* __restrict__ wt) {
    int idx = blockIdx.x * blockDim.x + threadIdx.x;   // n*256 + k
    int n = idx >> 8;
    int k = idx & 255;
    float v = 0.f;
    if (n < NOUT) v = (k < 128) ? Ws[k * NOUT + n] : Wn[(k - 128) * NOUT + n];
    wt[idx] = (unsigned short)f2b(v);
}

// ---------------- gather aggregation (bf16): agg[d] = invd[d] * sum h[s] ----------------
// ONE WAVE PER NODE: 4 edge slots (grp) x 16 lanes x 16 B.
__global__ void gather_agg_kernel(const unsigned short* __restrict__ h, const int* __restrict__ csr_src,
                                  const int* __restrict__ rowptr, const int* __restrict__ rowend,
                                  const float* __restrict__ invd,
                                  unsigned short* __restrict__ agg, int n_nodes) {
    int node = blockIdx.x * 4 + (threadIdx.x >> 6);
    if (node >= n_nodes) return;
    const int lane = threadIdx.x & 63;
    const int grp  = lane >> 4;        // edge slot 0..3
    const int q    = (lane & 15) * 8;  // bf16 offset within row
    const int start = rowptr[node];
    const int end   = rowend[node];

    float acc[8];
#pragma unroll
    for (int i = 0; i < 8; ++i) acc[i] = 0.f;

    int j = start + grp;
    for (; j + 4 < end; j += 8) {
        int s0 = csr_src[j];
        int s1 = csr_src[j + 4];
        uint4 v0 = *reinterpret_cast<const uint4*>(h + (size_t)s0 * HID + q);
        uint4 v1 = *reinterpret_cast<const uint4*>(h + (size_t)s1 * HID + q);
        acc[0] += b2f(v0.x & 0xffffu); acc[1] += b2f(v0.x >> 16);
        acc[2] += b2f(v0.y & 0xffffu); acc[3] += b2f(v0.y >> 16);
        acc[4] += b2f(v0.z & 0xffffu); acc[5] += b2f(v0.z >> 16);
        acc[6] += b2f(v0.w & 0xffffu); acc[7] += b2f(v0.w >> 16);
        acc[0] += b2f(v1.x & 0xffffu); acc[1] += b2f(v1.x >> 16);
        acc[2] += b2f(v1.y & 0xffffu); acc[3] += b2f(v1.y >> 16);
        acc[4] += b2f(v1.z & 0xffffu); acc[5] += b2f(v1.z >> 16);
        acc[6] += b2f(v1.w & 0xffffu); acc[7] += b2f(v1.w >> 16);
    }
    if (j < end) {
        int s0 = csr_src[j];
        uint4 v0 = *reinterpret_cast<const uint4*>(h + (size_t)s0 * HID + q);
        acc[0] += b2f(v0.x & 0xffffu); acc[1] += b2f(v0.x >> 16);
        acc[2] += b2f(v0.y & 0xffffu); acc[3] += b2f(v0.y >> 16);
        acc[4] += b2f(v0.z & 0xffffu); acc[5] += b2f(v0.z >> 16);
        acc[6] += b2f(v0.w & 0xffffu); acc[7] += b2f(v0.w >> 16);
    }

#pragma unroll
    for (int i = 0; i < 8; ++i) {
        acc[i] += __shfl_xor(acc[i], 16, 64);
        acc[i] += __shfl_xor(acc[i], 32, 64);
    }

    if (grp == 0) {
        float sc = invd[node];
        uint4 o;
        o.x = f2b(acc[0] * sc) | (f2b(acc[1] * sc) << 16);
        o.y = f2b(acc[2] * sc) | (f2b(acc[3] * sc) << 16);
        o.z = f2b(acc[4] * sc) | (f2b(acc[5] * sc) << 16);
        o.w = f2b(acc[6] * sc) | (f2b(acc[7] * sc) << 16);
        *reinterpret_cast<uint4*>(agg + (size_t)node * HID + q) = o;
    }
}

// same, but one wave per ACTIVE node; output compacted: agg[widx] for act[widx]
__global__ void gather_agg_act_kernel(const unsigned short* __restrict__ h, const int* __restrict__ csr_src,
                                      const int* __restrict__ rowptr, const int* __restrict__ rowend,
                                      const float* __restrict__ invd,
                                      const int* __restrict__ act, const int* __restrict__ n_act,
                                      unsigned short* __restrict__ agg) {
    int widx = blockIdx.x * 4 + (threadIdx.x >> 6);
    if (widx >= *n_act) return;
    int node = act[widx];
    const int lane = threadIdx.x & 63;
    const int grp  = lane >> 4;
    const int q    = (lane & 15) * 8;
    const int start = rowptr[node];
    const int end   = rowend[node];

    float acc[8];
#pragma unroll
    for (int i = 0; i < 8; ++i) acc[i] = 0.f;

    int j = start + grp;
    for (; j + 4 < end; j += 8) {
        int s0 = csr_src[j];
        int s1 = csr_src[j + 4];
        uint4 v0 = *reinterpret_cast<const uint4*>(h + (size_t)s0 * HID + q);
        uint4 v1 = *reinterpret_cast<const uint4*>(h + (size_t)s1 * HID + q);
        acc[0] += b2f(v0.x & 0xffffu); acc[1] += b2f(v0.x >> 16);
        acc[2] += b2f(v0.y & 0xffffu); acc[3] += b2f(v0.y >> 16);
        acc[4] += b2f(v0.z & 0xffffu); acc[5] += b2f(v0.z >> 16);
        acc[6] += b2f(v0.w & 0xffffu); acc[7] += b2f(v0.w >> 16);
        acc[0] += b2f(v1.x & 0xffffu); acc[1] += b2f(v1.x >> 16);
        acc[2] += b2f(v1.y & 0xffffu); acc[3] += b2f(v1.y >> 16);
        acc[4] += b2f(v1.z & 0xffffu); acc[5] += b2f(v1.z >> 16);
        acc[6] += b2f(v1.w & 0xffffu); acc[7] += b2f(v1.w >> 16);
    }
    if (j < end) {
        int s0 = csr_src[j];
        uint4 v0 = *reinterpret_cast<const uint4*>(h + (size_t)s0 * HID + q);
        acc[0] += b2f(v0.x & 0xffffu); acc[1] += b2f(v0.x >> 16);
        acc[2] += b2f(v0.y & 0xffffu); acc[3] += b2f(v0.y >> 16);
        acc[4] += b2f(v0.z & 0xffffu); acc[5] += b2f(v0.z >> 16);
        acc[6] += b2f(v0.w & 0xffffu); acc[7] += b2f(v0.w >> 16);
    }

#pragma unroll
    for (int i = 0; i < 8; ++i) {
        acc[i] += __shfl_xor(acc[i], 16, 64);
        acc[i] += __shfl_xor(acc[i], 32, 64);
    }

    if (grp == 0) {
        float sc = invd[node];
        uint4 o;
        o.x = f2b(acc[0] * sc) | (f2b(acc[1] * sc) << 16);
        o.y = f2b(acc[2] * sc) | (f2b(acc[3] * sc) << 16);
        o.z = f2b(acc[4] * sc) | (f2b(acc[5] * sc) << 16);
        o.w = f2b(acc[6] * sc) | (f2b(acc[7] * sc) << 16);
        *reinterpret_cast<uint4*>(agg + (size_t)widx * HID + q) = o;
    }
}

// ---------------- MFMA dual-GEMM + epilogue (full rows; used for layer 3) ----------------
template<int NOUT, bool HAS_MASK, bool OUT_BF16>
__global__ __launch_bounds__(256) void gemm_mfma(
    const unsigned short* __restrict__ Aself, const unsigned short* __restrict__ Aagg,
    const unsigned short* __restrict__ Wt,    // [NT*16][256] bf16
    const float* __restrict__ bias,
    const float* __restrict__ gh, const int* __restrict__ g2,
    const int* __restrict__ mask,
    void* __restrict__ outv, int n_rows)
{
    constexpr int NT = (NOUT + 15) / 16;
    const int lane = threadIdx.x & 63;
    const int wave = threadIdx.x >> 6;
    const int m16  = lane & 15;
    const int quad = lane >> 4;
    const int rowBase = blockIdx.x * 128 + wave * 32;

    f32x4 acc[2][NT];
#pragma unroll
    for (int mt = 0; mt < 2; ++mt)
#pragma unroll
        for (int t = 0; t < NT; ++t) acc[mt][t] = (f32x4){0.f, 0.f, 0.f, 0.f};

    const int koffq = quad * 8;
#pragma unroll
    for (int s = 0; s < 8; ++s) {
        const unsigned short* Ab = (s < 4) ? Aself : Aagg;
        const int ka = (s & 3) * 32 + koffq;
        bf16x8 a0 = *reinterpret_cast<const bf16x8*>(Ab + (size_t)(rowBase + m16) * HID + ka);
        bf16x8 a1 = *reinterpret_cast<const bf16x8*>(Ab + (size_t)(rowBase + 16 + m16) * HID + ka);
        const int kb = s * 32 + koffq;
#pragma unroll
        for (int t = 0; t < NT; ++t) {
            bf16x8 b = *reinterpret_cast<const bf16x8*>(Wt + (size_t)(t * 16 + m16) * 256 + kb);
            acc[0][t] = __builtin_amdgcn_mfma_f32_16x16x32_bf16(a0, b, acc[0][t], 0, 0, 0);
            acc[1][t] = __builtin_amdgcn_mfma_f32_16x16x32_bf16(a1, b, acc[1][t], 0, 0, 0);
        }
    }

#pragma unroll
    for (int mt = 0; mt < 2; ++mt) {
#pragma unroll
        for (int r = 0; r < 4; ++r) {
            int row = rowBase + mt * 16 + quad * 4 + r;
            if (row >= n_rows) continue;
            bool mk = true;
            const float* grow = nullptr;
            if (HAS_MASK) {
                mk = mask[row] != 0;
                if (!mk) grow = gh + (size_t)g2[row] * HID;
            }
#pragma unroll
            for (int t = 0; t < NT; ++t) {
                int col = t * 16 + m16;
                if (col >= NOUT) continue;
                float v = acc[mt][t][r] + bias[col];
                if (HAS_MASK) {
                    if (!mk) v = grow[col];
                    v = fmaxf(v, 0.f);
                }
                if (OUT_BF16)
                    ((unsigned short*)outv)[(size_t)row * NOUT + col] = (unsigned short)f2b(v);
                else
                    ((float*)outv)[(size_t)row * NOUT + col] = v;
            }
        }
    }
}

// ---------------- MFMA dual-GEMM over COMPACTED active rows (layers 1-2) ----------------
// A-self rows are act[compact_idx]; A-agg rows are compact-indexed; output scattered,
// relu(acc+bias) -> bf16.
__global__ __launch_bounds__(256) void gemm_mfma_act(
    const unsigned short* __restrict__ Aself, const unsigned short* __restrict__ Aagg,
    const unsigned short* __restrict__ Wt,    // [128][256] bf16
    const float* __restrict__ bias,
    const int* __restrict__ act, const int* __restrict__ n_act_p,
    unsigned short* __restrict__ out)
{
    constexpr int NT = 8;
    const int nA = *n_act_p;
    const int lane = threadIdx.x & 63;
    const int wave = threadIdx.x >> 6;
    const int m16  = lane & 15;
    const int quad = lane >> 4;
    const int rowBase = blockIdx.x * 128 + wave * 32;
    if (rowBase >= nA) return;

    const int cr0 = rowBase + m16;
    const int cr1 = rowBase + 16 + m16;
    const int g0 = (cr0 < nA) ? act[cr0] : 0;
    const int g1 = (cr1 < nA) ? act[cr1] : 0;

    f32x4 acc[2][NT];
#pragma unroll
    for (int mt = 0; mt < 2; ++mt)
#pragma unroll
        for (int t = 0; t < NT; ++t) acc[mt][t] = (f32x4){0.f, 0.f, 0.f, 0.f};

    const int koffq = quad * 8;
#pragma unroll
    for (int s = 0; s < 8; ++s) {
        const int ka = (s & 3) * 32 + koffq;
        bf16x8 a0, a1;
        if (s < 4) {
            a0 = *reinterpret_cast<const bf16x8*>(Aself + (size_t)g0 * HID + ka);
            a1 = *reinterpret_cast<const bf16x8*>(Aself + (size_t)g1 * HID + ka);
        } else {
            a0 = *reinterpret_cast<const bf16x8*>(Aagg + (size_t)cr0 * HID + ka);
            a1 = *reinterpret_cast<const bf16x8*>(Aagg + (size_t)cr1 * HID + ka);
        }
        const int kb = s * 32 + koffq;
#pragma unroll
        for (int t = 0; t < NT; ++t) {
            bf16x8 b = *reinterpret_cast<const bf16x8*>(Wt + (size_t)(t * 16 + m16) * 256 + kb);
            acc[0][t] = __builtin_amdgcn_mfma_f32_16x16x32_bf16(a0, b, acc[0][t], 0, 0, 0);
            acc[1][t] = __builtin_amdgcn_mfma_f32_16x16x32_bf16(a1, b, acc[1][t], 0, 0, 0);
        }
    }

#pragma unroll
    for (int mt = 0; mt < 2; ++mt) {
#pragma unroll
        for (int r = 0; r < 4; ++r) {
            int crow = rowBase + mt * 16 + quad * 4 + r;
            if (crow >= nA) continue;
            int orow = act[crow];
#pragma unroll
            for (int t = 0; t < NT; ++t) {
                int col = t * 16 + m16;
                float v = fmaxf(acc[mt][t][r] + bias[col], 0.f);
                out[(size_t)orow * HID + col] = (unsigned short)f2b(v);
            }
        }
    }
}

extern "C" void kernel_launch(void* const* d_in, const int* in_sizes, int n_in,
                              void* d_out, int out_size, void* d_ws, size_t ws_size,
                              hipStream_t stream) {
    const float* feat = (const float*)d_in[0];
    const float* gh   = (const float*)d_in[1];
    const float* gh2  = (const float*)d_in[2];
    const float* W1s  = (const float*)d_in[3];
    const float* W1n  = (const float*)d_in[4];
    const float* b1   = (const float*)d_in[5];
    const float* W2s  = (const float*)d_in[6];
    const float* W2n  = (const float*)d_in[7];
    const float* b2   = (const float*)d_in[8];
    const float* W3s  = (const float*)d_in[9];
    const float* W3n  = (const float*)d_in[10];
    const float* b3   = (const float*)d_in[11];
    const int* esrc   = (const int*)d_in[12];
    const int* edst   = (const int*)d_in[13];
    const int* g2     = (const int*)d_in[14];
    const int* mask   = (const int*)d_in[15];   // bool delivered as int32

    const int n_edges = in_sizes[12];
    const int n_nodes = in_sizes[14];
    const int n_pad   = ((n_nodes + 127) / 128) * 128;
    float* out = (float*)d_out;

    // workspace layout (16B aligned throughout)
    char* p = (char*)d_ws;
    int*   deg      = (int*)p;              p += (size_t)n_nodes * 4;
    int*   rowptr   = (int*)p;              p += (size_t)n_nodes * 4;
    int*   cursor   = (int*)p;              p += (size_t)n_nodes * 4;
    int*   bsums    = (int*)p;              p += 4096;
    float* invd     = (float*)p;            p += (size_t)n_nodes * 4;
    int*   csr_src  = (int*)p;              p += (size_t)n_edges * 4;
    unsigned short* hb0  = (unsigned short*)p; p += (size_t)n_pad * HID * 2;
    unsigned short* aggb = (unsigned short*)p; p += (size_t)n_pad * HID * 2;
    unsigned short* h1b  = (unsigned short*)p; p += (size_t)n_pad * HID * 2;
    unsigned short* h2b  = (unsigned short*)p; p += (size_t)n_pad * HID * 2;
    unsigned short* wt1  = (unsigned short*)p; p += (size_t)128 * 256 * 2;
    unsigned short* wt2  = (unsigned short*)p; p += (size_t)128 * 256 * 2;
    unsigned short* wt3  = (unsigned short*)p; p += (size_t)48  * 256 * 2;
    int*   excl_m   = (int*)p;              p += (size_t)n_nodes * 4;
    int*   bsums2   = (int*)p;              p += 4096;
    int*   act      = (int*)p;              p += (size_t)n_pad * 4;
    int*   n_act    = (int*)p;              p += 16;

    const int nb_scan = (n_nodes + SCAN_ELEMS - 1) / SCAN_ELEMS;
    const int gemm_blocks = (n_nodes + 127) / 128;
    const int agg_blocks  = (n_nodes + 3) / 4;    // 4 waves/block, 1 wave per node
    const int cvt4 = n_nodes * HID / 4;
    const int fill_threads = n_nodes * 16;

    // ---- CSR build ----
    hipMemsetAsync(deg, 0, (size_t)n_nodes * sizeof(int), stream);
    deg_count_kernel<<<(n_edges + 255) / 256, 256, 0, stream>>>(edst, deg, n_edges);
    scan1_kernel<<<nb_scan, SCAN_BS, 0, stream>>>(deg, rowptr, bsums, n_nodes);
    scan2_kernel<<<1, 256, 0, stream>>>(bsums, nb_scan);
    scan3_kernel<<<(n_nodes + 255) / 256, 256, 0, stream>>>(rowptr, bsums, cursor, deg, invd, n_nodes);
    fill_csr_kernel<<<(n_edges + 255) / 256, 256, 0, stream>>>(esrc, edst, cursor, csr_src, n_edges);

    // ---- mask compaction (active-row list) ----
    scan1_kernel<<<nb_scan, SCAN_BS, 0, stream>>>(mask, excl_m, bsums2, n_nodes);
    scan2_kernel<<<1, 256, 0, stream>>>(bsums2, nb_scan);
    scatter_act_kernel<<<(n_nodes + 255) / 256, 256, 0, stream>>>(mask, excl_m, bsums2, act, n_act, n_nodes);

    // ---- prep: bf16 features + transposed bf16 weights ----
    cvt_bf16_kernel<<<(cvt4 + 255) / 256, 256, 0, stream>>>(feat, hb0, cvt4);
    build_wt_kernel<128><<<128, 256, 0, stream>>>(W1s, W1n, wt1);
    build_wt_kernel<128><<<128, 256, 0, stream>>>(W2s, W2n, wt2);
    build_wt_kernel<40><<<48, 256, 0, stream>>>(W3s, W3n, wt3);

    // ---- layer 1: inactive rows = relu(gh[g2]); active rows = SAGE ----
    fill_inactive_kernel<<<(fill_threads + 255) / 256, 256, 0, stream>>>(mask, g2, gh, h1b, n_nodes);
    gather_agg_act_kernel<<<agg_blocks, 256, 0, stream>>>(hb0, csr_src, rowptr, cursor, invd, act, n_act, aggb);
    gemm_mfma_act<<<gemm_blocks, 256, 0, stream>>>(hb0, aggb, wt1, b1, act, n_act, h1b);

    // ---- layer 2 ----
    fill_inactive_kernel<<<(fill_threads + 255) / 256, 256, 0, stream>>>(mask, g2, gh2, h2b, n_nodes);
    gather_agg_act_kernel<<<agg_blocks, 256, 0, stream>>>(h1b, csr_src, rowptr, cursor, invd, act, n_act, aggb);
    gemm_mfma_act<<<gemm_blocks, 256, 0, stream>>>(h1b, aggb, wt2, b2, act, n_act, h2b);

    // ---- layer 3 (full rows, fp32 out, 40 cols) ----
    gather_agg_kernel<<<agg_blocks, 256, 0, stream>>>(h2b, csr_src, rowptr, cursor, invd, aggb, n_nodes);
    gemm_mfma<40, false, false><<<gemm_blocks, 256, 0, stream>>>(h2b, aggb, wt3, b3, nullptr, nullptr, nullptr, out, n_nodes);
}

// Round 2
// 835.135 us; speedup vs baseline: 1.2649x; 1.0267x over previous
//
#include <hip/hip_runtime.h>

#define HID 128

typedef __bf16 bf16x8 __attribute__((ext_vector_type(8)));
typedef float  f32x4  __attribute__((ext_vector_type(4)));

__device__ __forceinline__ unsigned f2b(float x) {           // fp32 -> bf16 bits, RNE
    unsigned u = __float_as_uint(x);
    return (u + 0x7fffu + ((u >> 16) & 1u)) >> 16;
}
__device__ __forceinline__ float b2f(unsigned b) {           // bf16 bits -> fp32
    return __uint_as_float(b << 16);
}

// ---------------- CSR build ----------------
__global__ void deg_count_kernel(const int* __restrict__ dst, int* __restrict__ deg, int n_edges) {
    int e = blockIdx.x * blockDim.x + threadIdx.x;
    if (e < n_edges) atomicAdd(&deg[dst[e]], 1);
}

#define SCAN_BS 256
#define SCAN_ELEMS 1024  // 4 per thread

// dual scan: deg -> exclA/bsumsA  and  mask -> exclB/bsumsB in one launch
__global__ void scan1_dual_kernel(const int* __restrict__ a, int* __restrict__ excl_a,
                                  int* __restrict__ bsums_a,
                                  const int* __restrict__ b, int* __restrict__ excl_b,
                                  int* __restrict__ bsums_b, int n) {
    __shared__ int s[SCAN_BS];
    int base = blockIdx.x * SCAN_ELEMS + threadIdx.x * 4;
    // ---- pass A ----
    {
        int v[4]; int t = 0;
#pragma unroll
        for (int i = 0; i < 4; ++i) { int idx = base + i; v[i] = (idx < n) ? a[idx] : 0; t += v[i]; }
        s[threadIdx.x] = t;
        __syncthreads();
        for (int off = 1; off < SCAN_BS; off <<= 1) {
            int x = (threadIdx.x >= off) ? s[threadIdx.x - off] : 0;
            __syncthreads();
            s[threadIdx.x] += x;
            __syncthreads();
        }
        int run = s[threadIdx.x] - t;
#pragma unroll
        for (int i = 0; i < 4; ++i) { int idx = base + i; if (idx < n) excl_a[idx] = run; run += v[i]; }
        if (threadIdx.x == SCAN_BS - 1) bsums_a[blockIdx.x] = s[SCAN_BS - 1];
    }
    __syncthreads();
    // ---- pass B ----
    {
        int v[4]; int t = 0;
#pragma unroll
        for (int i = 0; i < 4; ++i) { int idx = base + i; v[i] = (idx < n) ? b[idx] : 0; t += v[i]; }
        s[threadIdx.x] = t;
        __syncthreads();
        for (int off = 1; off < SCAN_BS; off <<= 1) {
            int x = (threadIdx.x >= off) ? s[threadIdx.x - off] : 0;
            __syncthreads();
            s[threadIdx.x] += x;
            __syncthreads();
        }
        int run = s[threadIdx.x] - t;
#pragma unroll
        for (int i = 0; i < 4; ++i) { int idx = base + i; if (idx < n) excl_b[idx] = run; run += v[i]; }
        if (threadIdx.x == SCAN_BS - 1) bsums_b[blockIdx.x] = s[SCAN_BS - 1];
    }
}

// single-block exclusive scan of both blockSums arrays (nb <= 256)
__global__ void scan2_dual_kernel(int* __restrict__ bsa, int* __restrict__ bsb, int nb) {
    __shared__ int s[256];
    int i = threadIdx.x;
    {
        int v = (i < nb) ? bsa[i] : 0;
        s[i] = v;
        __syncthreads();
        for (int off = 1; off < 256; off <<= 1) {
            int x = (i >= off) ? s[i - off] : 0;
            __syncthreads();
            s[i] += x;
            __syncthreads();
        }
        if (i < nb) bsa[i] = s[i] - v;
    }
    __syncthreads();
    {
        int v = (i < nb) ? bsb[i] : 0;
        s[i] = v;
        __syncthreads();
        for (int off = 1; off < 256; off <<= 1) {
            int x = (i >= off) ? s[i - off] : 0;
            __syncthreads();
            s[i] += x;
            __syncthreads();
        }
        if (i < nb) bsb[i] = s[i] - v;
    }
}

// rowptr/cursor/invd finalize + active-list scatter, fused
__global__ void scan3_fused_kernel(int* __restrict__ rowptr, const int* __restrict__ bsumsA,
                                   int* __restrict__ cursor, const int* __restrict__ deg,
                                   float* __restrict__ invd,
                                   const int* __restrict__ mask, const int* __restrict__ exclM,
                                   const int* __restrict__ bsumsB, int* __restrict__ act,
                                   int* __restrict__ n_act, int n) {
    int i = blockIdx.x * blockDim.x + threadIdx.x;
    if (i < n) {
        int v = rowptr[i] + bsumsA[i >> 10];
        rowptr[i] = v;
        cursor[i] = v;
        invd[i] = 1.0f / fmaxf((float)deg[i], 1.0f);
        int pos = exclM[i] + bsumsB[i >> 10];
        if (mask[i]) act[pos] = i;
        if (i == n - 1) *n_act = pos + (mask[i] ? 1 : 0);
    }
}

__global__ void fill_csr_kernel(const int* __restrict__ src, const int* __restrict__ dst,
                                int* __restrict__ cursor, int* __restrict__ csr_src, int n_edges) {
    int e = blockIdx.x * blockDim.x + threadIdx.x;
    if (e < n_edges) {
        int pos = atomicAdd(&cursor[dst[e]], 1);
        csr_src[pos] = src[e];
    }
}
// after fill_csr, cursor[i] == rowptr[i] + deg[i]  -> reused as row-end pointer

// inactive rows: h[row] = relu(gh[g2[row]])  (bf16 out). 16 threads per row, 8 cols each.
__global__ void fill_inactive_kernel(const int* __restrict__ mask, const int* __restrict__ g2,
                                     const float* __restrict__ gh, unsigned short* __restrict__ out,
                                     int n_nodes) {
    int idx = blockIdx.x * blockDim.x + threadIdx.x;
    int row = idx >> 4;
    if (row >= n_nodes || mask[row]) return;
    int c = (idx & 15) * 8;
    const float* src = gh + (size_t)g2[row] * HID + c;
    float4 v0 = reinterpret_cast<const float4*>(src)[0];
    float4 v1 = reinterpret_cast<const float4*>(src)[1];
    uint4 o;
    o.x = f2b(fmaxf(v0.x, 0.f)) | (f2b(fmaxf(v0.y, 0.f)) << 16);
    o.y = f2b(fmaxf(v0.z, 0.f)) | (f2b(fmaxf(v0.w, 0.f)) << 16);
    o.z = f2b(fmaxf(v1.x, 0.f)) | (f2b(fmaxf(v1.y, 0.f)) << 16);
    o.w = f2b(fmaxf(v1.z, 0.f)) | (f2b(fmaxf(v1.w, 0.f)) << 16);
    *reinterpret_cast<uint4*>(out + (size_t)row * HID + c) = o;
}

// ---------------- fp32 -> bf16 feature convert ----------------
__global__ void cvt_bf16_kernel(const float* __restrict__ in, unsigned short* __restrict__ out, int total4) {
    int i = blockIdx.x * blockDim.x + threadIdx.x;
    if (i >= total4) return;
    float4 v = reinterpret_cast<const float4*>(in)[i];
    uint2 o;
    o.x = f2b(v.x) | (f2b(v.y) << 16);
    o.y = f2b(v.z) | (f2b(v.w) << 16);
    reinterpret_cast<uint2*>(out)[i] = o;
}

// ---------------- weight prep: Wt[n][k] bf16, k = [Ws rows | Wn rows] (layers 1-2) ----------------
template<int NOUT>
__global__ void build_wt_kernel(const float* __restrict__ Ws, const float* __restrict__ Wn,
                                unsigned short* __restrict__ wt) {
    int idx = blockIdx.x * blockDim.x + threadIdx.x;   // n*256 + k
    int n = idx >> 8;
    int k = idx & 255;
    float v = 0.f;
    if (n < NOUT) v = (k < 128) ? Ws[k * NOUT + n] : Wn[(k - 128) * NOUT + n];
    wt[idx] = (unsigned short)f2b(v);
}

// layer-3 combined weight: [112][128] bf16.  n<48: W3s col n (40 used);
// n>=48: W3n col (n-48), zero-padded to 64 so y3 dims 40..63 come out 0.
__global__ void build_wt3b_kernel(const float* __restrict__ Ws, const float* __restrict__ Wn,
                                  unsigned short* __restrict__ wt) {
    int idx = blockIdx.x * blockDim.x + threadIdx.x;   // n*128 + k, 112*128 total
    int n = idx >> 7;
    int k = idx & 127;
    float v = 0.f;
    if (n < 48) { if (n < 40) v = Ws[k * 40 + n]; }
    else        { int c = n - 48; if (c < 40) v = Wn[k * 40 + c]; }
    wt[idx] = (unsigned short)f2b(v);
}

// ---------------- gather aggregation over ACTIVE nodes (layers 1-2) ----------------
// ONE WAVE PER ACTIVE NODE: 4 edge slots x 16 lanes x 16 B; compacted output.
__global__ void gather_agg_act_kernel(const unsigned short* __restrict__ h, const int* __restrict__ csr_src,
                                      const int* __restrict__ rowptr, const int* __restrict__ rowend,
                                      const float* __restrict__ invd,
                                      const int* __restrict__ act, const int* __restrict__ n_act,
                                      unsigned short* __restrict__ agg) {
    int widx = blockIdx.x * 4 + (threadIdx.x >> 6);
    if (widx >= *n_act) return;
    int node = act[widx];
    const int lane = threadIdx.x & 63;
    const int grp  = lane >> 4;
    const int q    = (lane & 15) * 8;
    const int start = rowptr[node];
    const int end   = rowend[node];

    float acc[8];
#pragma unroll
    for (int i = 0; i < 8; ++i) acc[i] = 0.f;

    int j = start + grp;
    for (; j + 4 < end; j += 8) {
        int s0 = csr_src[j];
        int s1 = csr_src[j + 4];
        uint4 v0 = *reinterpret_cast<const uint4*>(h + (size_t)s0 * HID + q);
        uint4 v1 = *reinterpret_cast<const uint4*>(h + (size_t)s1 * HID + q);
        acc[0] += b2f(v0.x & 0xffffu); acc[1] += b2f(v0.x >> 16);
        acc[2] += b2f(v0.y & 0xffffu); acc[3] += b2f(v0.y >> 16);
        acc[4] += b2f(v0.z & 0xffffu); acc[5] += b2f(v0.z >> 16);
        acc[6] += b2f(v0.w & 0xffffu); acc[7] += b2f(v0.w >> 16);
        acc[0] += b2f(v1.x & 0xffffu); acc[1] += b2f(v1.x >> 16);
        acc[2] += b2f(v1.y & 0xffffu); acc[3] += b2f(v1.y >> 16);
        acc[4] += b2f(v1.z & 0xffffu); acc[5] += b2f(v1.z >> 16);
        acc[6] += b2f(v1.w & 0xffffu); acc[7] += b2f(v1.w >> 16);
    }
    if (j < end) {
        int s0 = csr_src[j];
        uint4 v0 = *reinterpret_cast<const uint4*>(h + (size_t)s0 * HID + q);
        acc[0] += b2f(v0.x & 0xffffu); acc[1] += b2f(v0.x >> 16);
        acc[2] += b2f(v0.y & 0xffffu); acc[3] += b2f(v0.y >> 16);
        acc[4] += b2f(v0.z & 0xffffu); acc[5] += b2f(v0.z >> 16);
        acc[6] += b2f(v0.w & 0xffffu); acc[7] += b2f(v0.w >> 16);
    }

#pragma unroll
    for (int i = 0; i < 8; ++i) {
        acc[i] += __shfl_xor(acc[i], 16, 64);
        acc[i] += __shfl_xor(acc[i], 32, 64);
    }

    if (grp == 0) {
        float sc = invd[node];
        uint4 o;
        o.x = f2b(acc[0] * sc) | (f2b(acc[1] * sc) << 16);
        o.y = f2b(acc[2] * sc) | (f2b(acc[3] * sc) << 16);
        o.z = f2b(acc[4] * sc) | (f2b(acc[5] * sc) << 16);
        o.w = f2b(acc[6] * sc) | (f2b(acc[7] * sc) << 16);
        *reinterpret_cast<uint4*>(agg + (size_t)widx * HID + q) = o;
    }
}

// ---------------- MFMA dual-GEMM over COMPACTED active rows (layers 1-2) ----------------
__global__ __launch_bounds__(256) void gemm_mfma_act(
    const unsigned short* __restrict__ Aself, const unsigned short* __restrict__ Aagg,
    const unsigned short* __restrict__ Wt,    // [128][256] bf16
    const float* __restrict__ bias,
    const int* __restrict__ act, const int* __restrict__ n_act_p,
    unsigned short* __restrict__ out)
{
    constexpr int NT = 8;
    const int nA = *n_act_p;
    const int lane = threadIdx.x & 63;
    const int wave = threadIdx.x >> 6;
    const int m16  = lane & 15;
    const int quad = lane >> 4;
    const int rowBase = blockIdx.x * 128 + wave * 32;
    if (rowBase >= nA) return;

    const int cr0 = rowBase + m16;
    const int cr1 = rowBase + 16 + m16;
    const int g0 = (cr0 < nA) ? act[cr0] : 0;
    const int g1 = (cr1 < nA) ? act[cr1] : 0;

    f32x4 acc[2][NT];
#pragma unroll
    for (int mt = 0; mt < 2; ++mt)
#pragma unroll
        for (int t = 0; t < NT; ++t) acc[mt][t] = (f32x4){0.f, 0.f, 0.f, 0.f};

    const int koffq = quad * 8;
#pragma unroll
    for (int s = 0; s < 8; ++s) {
        const int ka = (s & 3) * 32 + koffq;
        bf16x8 a0, a1;
        if (s < 4) {
            a0 = *reinterpret_cast<const bf16x8*>(Aself + (size_t)g0 * HID + ka);
            a1 = *reinterpret_cast<const bf16x8*>(Aself + (size_t)g1 * HID + ka);
        } else {
            a0 = *reinterpret_cast<const bf16x8*>(Aagg + (size_t)cr0 * HID + ka);
            a1 = *reinterpret_cast<const bf16x8*>(Aagg + (size_t)cr1 * HID + ka);
        }
        const int kb = s * 32 + koffq;
#pragma unroll
        for (int t = 0; t < NT; ++t) {
            bf16x8 b = *reinterpret_cast<const bf16x8*>(Wt + (size_t)(t * 16 + m16) * 256 + kb);
            acc[0][t] = __builtin_amdgcn_mfma_f32_16x16x32_bf16(a0, b, acc[0][t], 0, 0, 0);
            acc[1][t] = __builtin_amdgcn_mfma_f32_16x16x32_bf16(a1, b, acc[1][t], 0, 0, 0);
        }
    }

#pragma unroll
    for (int mt = 0; mt < 2; ++mt) {
#pragma unroll
        for (int r = 0; r < 4; ++r) {
            int crow = rowBase + mt * 16 + quad * 4 + r;
            if (crow >= nA) continue;
            int orow = act[crow];
#pragma unroll
            for (int t = 0; t < NT; ++t) {
                int col = t * 16 + m16;
                float v = fmaxf(acc[mt][t][r] + bias[col], 0.f);
                out[(size_t)orow * HID + col] = (unsigned short)f2b(v);
            }
        }
    }
}

// ---------------- layer-3 projection GEMM: out = h2@W3s + b3 (fp32), y3 = bf16(h2@W3n) ----------------
// Wt: [112][128].  cols 0..39 -> out, cols 48..111 -> y3 dims 0..63 (zero-padded weights).
__global__ __launch_bounds__(256) void gemm_proj3(
    const unsigned short* __restrict__ Aself,
    const unsigned short* __restrict__ Wt,
    const float* __restrict__ bias,
    float* __restrict__ out, unsigned short* __restrict__ y3, int n_rows)
{
    constexpr int NT = 7;
    const int lane = threadIdx.x & 63;
    const int wave = threadIdx.x >> 6;
    const int m16  = lane & 15;
    const int quad = lane >> 4;
    const int rowBase = blockIdx.x * 128 + wave * 32;

    f32x4 acc[2][NT];
#pragma unroll
    for (int mt = 0; mt < 2; ++mt)
#pragma unroll
        for (int t = 0; t < NT; ++t) acc[mt][t] = (f32x4){0.f, 0.f, 0.f, 0.f};

    const int koffq = quad * 8;
#pragma unroll
    for (int s = 0; s < 4; ++s) {
        const int ka = s * 32 + koffq;
        bf16x8 a0 = *reinterpret_cast<const bf16x8*>(Aself + (size_t)(rowBase + m16) * HID + ka);
        bf16x8 a1 = *reinterpret_cast<const bf16x8*>(Aself + (size_t)(rowBase + 16 + m16) * HID + ka);
#pragma unroll
        for (int t = 0; t < NT; ++t) {
            bf16x8 b = *reinterpret_cast<const bf16x8*>(Wt + (size_t)(t * 16 + m16) * 128 + ka);
            acc[0][t] = __builtin_amdgcn_mfma_f32_16x16x32_bf16(a0, b, acc[0][t], 0, 0, 0);
            acc[1][t] = __builtin_amdgcn_mfma_f32_16x16x32_bf16(a1, b, acc[1][t], 0, 0, 0);
        }
    }

#pragma unroll
    for (int mt = 0; mt < 2; ++mt) {
#pragma unroll
        for (int r = 0; r < 4; ++r) {
            int row = rowBase + mt * 16 + quad * 4 + r;
            if (row >= n_rows) continue;
#pragma unroll
            for (int t = 0; t < NT; ++t) {
                int col = t * 16 + m16;
                float v = acc[mt][t][r];
                if (col < 40) {
                    out[(size_t)row * 40 + col] = v + bias[col];
                } else if (col >= 48) {
                    y3[(size_t)row * 64 + (col - 48)] = (unsigned short)f2b(v);
                }
            }
        }
    }
}

// ---------------- layer-3 aggregation over projected rows + RMW epilogue ----------------
// ONE WAVE PER NODE: 8 edge slots x 8 lanes x 16 B (y3 rows: 64 bf16 = 128 B).
// out[node][0..39] += invd * sum_{src} y3[src][0..39]
__global__ void gather_add3_kernel(const unsigned short* __restrict__ y3, const int* __restrict__ csr_src,
                                   const int* __restrict__ rowptr, const int* __restrict__ rowend,
                                   const float* __restrict__ invd,
                                   float* __restrict__ out, int n_nodes) {
    int node = blockIdx.x * 4 + (threadIdx.x >> 6);
    if (node >= n_nodes) return;
    const int lane = threadIdx.x & 63;
    const int grp  = lane >> 3;        // edge slot 0..7
    const int q    = (lane & 7) * 8;   // bf16 offset within 64-dim row
    const int start = rowptr[node];
    const int end   = rowend[node];

    float acc[8];
#pragma unroll
    for (int i = 0; i < 8; ++i) acc[i] = 0.f;

    int j = start + grp;
    for (; j + 8 < end; j += 16) {
        int s0 = csr_src[j];
        int s1 = csr_src[j + 8];
        uint4 v0 = *reinterpret_cast<const uint4*>(y3 + (size_t)s0 * 64 + q);
        uint4 v1 = *reinterpret_cast<const uint4*>(y3 + (size_t)s1 * 64 + q);
        acc[0] += b2f(v0.x & 0xffffu); acc[1] += b2f(v0.x >> 16);
        acc[2] += b2f(v0.y & 0xffffu); acc[3] += b2f(v0.y >> 16);
        acc[4] += b2f(v0.z & 0xffffu); acc[5] += b2f(v0.z >> 16);
        acc[6] += b2f(v0.w & 0xffffu); acc[7] += b2f(v0.w >> 16);
        acc[0] += b2f(v1.x & 0xffffu); acc[1] += b2f(v1.x >> 16);
        acc[2] += b2f(v1.y & 0xffffu); acc[3] += b2f(v1.y >> 16);
        acc[4] += b2f(v1.z & 0xffffu); acc[5] += b2f(v1.z >> 16);
        acc[6] += b2f(v1.w & 0xffffu); acc[7] += b2f(v1.w >> 16);
    }
    if (j < end) {
        int s0 = csr_src[j];
        uint4 v0 = *reinterpret_cast<const uint4*>(y3 + (size_t)s0 * 64 + q);
        acc[0] += b2f(v0.x & 0xffffu); acc[1] += b2f(v0.x >> 16);
        acc[2] += b2f(v0.y & 0xffffu); acc[3] += b2f(v0.y >> 16);
        acc[4] += b2f(v0.z & 0xffffu); acc[5] += b2f(v0.z >> 16);
        acc[6] += b2f(v0.w & 0xffffu); acc[7] += b2f(v0.w >> 16);
    }

    // reduce across the 8 edge slots (lane bits 3,4,5)
#pragma unroll
    for (int i = 0; i < 8; ++i) {
        acc[i] += __shfl_xor(acc[i], 8, 64);
        acc[i] += __shfl_xor(acc[i], 16, 64);
        acc[i] += __shfl_xor(acc[i], 32, 64);
    }

    if (grp == 0 && lane < 5) {         // lanes 0..4 cover dims 0..39
        float sc = invd[node];
        float* o = out + (size_t)node * 40 + lane * 8;
        float4 lo = reinterpret_cast<float4*>(o)[0];
        float4 hi = reinterpret_cast<float4*>(o)[1];
        lo.x += acc[0] * sc; lo.y += acc[1] * sc; lo.z += acc[2] * sc; lo.w += acc[3] * sc;
        hi.x += acc[4] * sc; hi.y += acc[5] * sc; hi.z += acc[6] * sc; hi.w += acc[7] * sc;
        reinterpret_cast<float4*>(o)[0] = lo;
        reinterpret_cast<float4*>(o)[1] = hi;
    }
}

extern "C" void kernel_launch(void* const* d_in, const int* in_sizes, int n_in,
                              void* d_out, int out_size, void* d_ws, size_t ws_size,
                              hipStream_t stream) {
    const float* feat = (const float*)d_in[0];
    const float* gh   = (const float*)d_in[1];
    const float* gh2  = (const float*)d_in[2];
    const float* W1s  = (const float*)d_in[3];
    const float* W1n  = (const float*)d_in[4];
    const float* b1   = (const float*)d_in[5];
    const float* W2s  = (const float*)d_in[6];
    const float* W2n  = (const float*)d_in[7];
    const float* b2   = (const float*)d_in[8];
    const float* W3s  = (const float*)d_in[9];
    const float* W3n  = (const float*)d_in[10];
    const float* b3   = (const float*)d_in[11];
    const int* esrc   = (const int*)d_in[12];
    const int* edst   = (const int*)d_in[13];
    const int* g2     = (const int*)d_in[14];
    const int* mask   = (const int*)d_in[15];   // bool delivered as int32

    const int n_edges = in_sizes[12];
    const int n_nodes = in_sizes[14];
    const int n_pad   = ((n_nodes + 127) / 128) * 128;
    float* out = (float*)d_out;

    // workspace layout (16B aligned throughout)
    char* p = (char*)d_ws;
    int*   deg      = (int*)p;              p += (size_t)n_nodes * 4;
    int*   rowptr   = (int*)p;              p += (size_t)n_nodes * 4;
    int*   cursor   = (int*)p;              p += (size_t)n_nodes * 4;
    int*   bsums    = (int*)p;              p += 4096;
    float* invd     = (float*)p;            p += (size_t)n_nodes * 4;
    int*   csr_src  = (int*)p;              p += (size_t)n_edges * 4;
    unsigned short* hb0  = (unsigned short*)p; p += (size_t)n_pad * HID * 2;
    unsigned short* aggb = (unsigned short*)p; p += (size_t)n_pad * HID * 2;
    unsigned short* h1b  = (unsigned short*)p; p += (size_t)n_pad * HID * 2;
    unsigned short* h2b  = (unsigned short*)p; p += (size_t)n_pad * HID * 2;
    unsigned short* wt1  = (unsigned short*)p; p += (size_t)128 * 256 * 2;
    unsigned short* wt2  = (unsigned short*)p; p += (size_t)128 * 256 * 2;
    unsigned short* wt3b = (unsigned short*)p; p += (size_t)112 * 128 * 2;
    int*   excl_m   = (int*)p;              p += (size_t)n_nodes * 4;
    int*   bsums2   = (int*)p;              p += 4096;
    int*   act      = (int*)p;              p += (size_t)n_pad * 4;
    int*   n_act    = (int*)p;              p += 16;
    // y3 (layer-3 projected neigh rows, [n_pad][64] bf16) aliases aggb (dead in layer 3)
    unsigned short* y3 = aggb;

    const int nb_scan = (n_nodes + SCAN_ELEMS - 1) / SCAN_ELEMS;
    const int gemm_blocks = (n_nodes + 127) / 128;
    const int agg_blocks  = (n_nodes + 3) / 4;    // 4 waves/block, 1 wave per node
    const int cvt4 = n_nodes * HID / 4;
    const int fill_threads = n_nodes * 16;

    // ---- CSR build + mask compaction (fused scans) ----
    hipMemsetAsync(deg, 0, (size_t)n_nodes * sizeof(int), stream);
    deg_count_kernel<<<(n_edges + 255) / 256, 256, 0, stream>>>(edst, deg, n_edges);
    scan1_dual_kernel<<<nb_scan, SCAN_BS, 0, stream>>>(deg, rowptr, bsums, mask, excl_m, bsums2, n_nodes);
    scan2_dual_kernel<<<1, 256, 0, stream>>>(bsums, bsums2, nb_scan);
    scan3_fused_kernel<<<(n_nodes + 255) / 256, 256, 0, stream>>>(rowptr, bsums, cursor, deg, invd,
                                                                  mask, excl_m, bsums2, act, n_act, n_nodes);
    fill_csr_kernel<<<(n_edges + 255) / 256, 256, 0, stream>>>(esrc, edst, cursor, csr_src, n_edges);

    // ---- prep: bf16 features + transposed bf16 weights ----
    cvt_bf16_kernel<<<(cvt4 + 255) / 256, 256, 0, stream>>>(feat, hb0, cvt4);
    build_wt_kernel<128><<<128, 256, 0, stream>>>(W1s, W1n, wt1);
    build_wt_kernel<128><<<128, 256, 0, stream>>>(W2s, W2n, wt2);
    build_wt3b_kernel<<<56, 256, 0, stream>>>(W3s, W3n, wt3b);

    // ---- layer 1: inactive rows = relu(gh[g2]); active rows = SAGE ----
    fill_inactive_kernel<<<(fill_threads + 255) / 256, 256, 0, stream>>>(mask, g2, gh, h1b, n_nodes);
    gather_agg_act_kernel<<<agg_blocks, 256, 0, stream>>>(hb0, csr_src, rowptr, cursor, invd, act, n_act, aggb);
    gemm_mfma_act<<<gemm_blocks, 256, 0, stream>>>(hb0, aggb, wt1, b1, act, n_act, h1b);

    // ---- layer 2 ----
    fill_inactive_kernel<<<(fill_threads + 255) / 256, 256, 0, stream>>>(mask, g2, gh2, h2b, n_nodes);
    gather_agg_act_kernel<<<agg_blocks, 256, 0, stream>>>(h1b, csr_src, rowptr, cursor, invd, act, n_act, aggb);
    gemm_mfma_act<<<gemm_blocks, 256, 0, stream>>>(h1b, aggb, wt2, b2, act, n_act, h2b);

    // ---- layer 3: project first (agg is linear), then 40-dim aggregation ----
    // out = h2@W3s + b3 ; y3 = bf16(h2@W3n) zero-padded to 64 dims
    gemm_proj3<<<gemm_blocks, 256, 0, stream>>>(h2b, wt3b, b3, out, y3, n_nodes);
    // out += invd * sum_src y3[src]
    gather_add3_kernel<<<agg_blocks, 256, 0, stream>>>(y3, csr_src, rowptr, cursor, invd, out, n_nodes);
}